// Round 1
// baseline (1439.650 us; speedup 1.0000x reference)
//
#include <hip/hip_runtime.h>
#include <math.h>

#define N_NODES 20000
#define E_EDGES 320000
#define ET (E_EDGES + N_NODES)   // edges incl. self-loops
#define C_HID 640
#define NEG_SLOPE 0.2f

__device__ __forceinline__ float leaky(float x) { return x > 0.f ? x : NEG_SLOPE * x; }

// ---------------- CSR build (by dst) ----------------
__global__ void k_zero(int* p, int n) {
    int i = blockIdx.x * blockDim.x + threadIdx.x;
    if (i < n) p[i] = 0;
}

__global__ void k_count(const int* __restrict__ ei, int* __restrict__ counts) {
    int j = blockIdx.x * blockDim.x + threadIdx.x;
    if (j >= ET) return;
    int d = (j < E_EDGES) ? ei[E_EDGES + j] : (j - E_EDGES);
    atomicAdd(&counts[d], 1);
}

// single-block inclusive scan -> rowptr (N+1)
__global__ void k_scan(const int* __restrict__ counts, int* __restrict__ rowptr) {
    __shared__ int buf[1024];
    __shared__ int carry;
    int t = threadIdx.x;
    if (t == 0) { carry = 0; rowptr[0] = 0; }
    __syncthreads();
    for (int base = 0; base < N_NODES; base += 1024) {
        int i = base + t;
        int v = (i < N_NODES) ? counts[i] : 0;
        buf[t] = v;
        __syncthreads();
        for (int off = 1; off < 1024; off <<= 1) {
            int x = (t >= off) ? buf[t - off] : 0;
            __syncthreads();
            buf[t] += x;
            __syncthreads();
        }
        int incl = buf[t] + carry;
        if (i < N_NODES) rowptr[i + 1] = incl;
        __syncthreads();
        if (t == 1023) carry = incl;
        __syncthreads();
    }
}

__global__ void k_copy(const int* __restrict__ a, int* __restrict__ b, int n) {
    int i = blockIdx.x * blockDim.x + threadIdx.x;
    if (i < n) b[i] = a[i];
}

__global__ void k_fill(const int* __restrict__ ei, int* __restrict__ cursor, int* __restrict__ col) {
    int j = blockIdx.x * blockDim.x + threadIdx.x;
    if (j >= ET) return;
    int s, d;
    if (j < E_EDGES) { s = ei[j]; d = ei[E_EDGES + j]; }
    else { s = d = j - E_EDGES; }
    int pos = atomicAdd(&cursor[d], 1);
    col[pos] = s;
}

// ---------------- fp32 tiled GEMM: C[M,Nc] = A[M,K] @ B[K,Nc] ----------------
// BM=BN=64, BK=16, 256 threads, 4x4 per thread. K % 16 == 0, Nc % 64 == 0.
__global__ __launch_bounds__(256) void k_gemm(const float* __restrict__ A,
                                              const float* __restrict__ B,
                                              float* __restrict__ C,
                                              int M, int K, int Nc) {
    __shared__ float As[16][64];
    __shared__ float Bs[16][64];
    int t  = threadIdx.x;
    int tx = t & 15, ty = t >> 4;
    int rowBase = blockIdx.x * 64;
    int colBase = blockIdx.y * 64;
    float acc[4][4] = {};
    int am = t >> 2;           // 0..63 A-tile row
    int ak = (t & 3) * 4;      // 0,4,8,12
    int bk = t >> 4;           // 0..15 B-tile k
    int bn = (t & 15) * 4;
    for (int k0 = 0; k0 < K; k0 += 16) {
        int gm = rowBase + am;
        float4 av = make_float4(0.f, 0.f, 0.f, 0.f);
        if (gm < M) av = *(const float4*)&A[(size_t)gm * K + k0 + ak];
        As[ak + 0][am] = av.x; As[ak + 1][am] = av.y;
        As[ak + 2][am] = av.z; As[ak + 3][am] = av.w;
        float4 bv = *(const float4*)&B[(size_t)(k0 + bk) * Nc + colBase + bn];
        *(float4*)&Bs[bk][bn] = bv;
        __syncthreads();
#pragma unroll
        for (int k = 0; k < 16; k++) {
            float4 a4 = *(const float4*)&As[k][ty * 4];
            float4 b4 = *(const float4*)&Bs[k][tx * 4];
            float a_[4] = {a4.x, a4.y, a4.z, a4.w};
            float b_[4] = {b4.x, b4.y, b4.z, b4.w};
#pragma unroll
            for (int i = 0; i < 4; i++)
#pragma unroll
                for (int j = 0; j < 4; j++)
                    acc[i][j] = fmaf(a_[i], b_[j], acc[i][j]);
        }
        __syncthreads();
    }
#pragma unroll
    for (int i = 0; i < 4; i++) {
        int r = rowBase + ty * 4 + i;
        if (r >= M) continue;
#pragma unroll
        for (int j = 0; j < 4; j++)
            C[(size_t)r * Nc + colBase + tx * 4 + j] = acc[i][j];
    }
}

// ---------------- per-node attention logits (Co=640): wave per node ----------------
__global__ __launch_bounds__(256) void k_logits(const float* __restrict__ hW,
                                                const float* __restrict__ asrc,
                                                const float* __restrict__ adst,
                                                float* __restrict__ as_, float* __restrict__ ad_) {
    int wave = (blockIdx.x * blockDim.x + threadIdx.x) >> 6;
    int lane = threadIdx.x & 63;
    if (wave >= N_NODES) return;
    const float* row = hW + (size_t)wave * C_HID;
    float ps = 0.f, pd = 0.f;
#pragma unroll
    for (int k = lane; k < C_HID; k += 64) {
        float v = row[k];
        ps = fmaf(v, asrc[k], ps);
        pd = fmaf(v, adst[k], pd);
    }
    for (int o = 32; o; o >>= 1) { ps += __shfl_xor(ps, o); pd += __shfl_xor(pd, o); }
    if (lane == 0) { as_[wave] = ps; ad_[wave] = pd; }
}

// ---------------- softmax + weighted aggregation (Co=640): wave per dst node ----------------
__global__ __launch_bounds__(256) void k_agg640(const float* __restrict__ hW,
                                                const float* __restrict__ as_,
                                                const float* __restrict__ ad_,
                                                const int* __restrict__ rowptr,
                                                const int* __restrict__ col,
                                                const float* __restrict__ bias,
                                                float* __restrict__ out, int do_relu) {
    int wave = (blockIdx.x * blockDim.x + threadIdx.x) >> 6;
    int lane = threadIdx.x & 63;
    if (wave >= N_NODES) return;
    int i = wave;
    int start = rowptr[i], end = rowptr[i + 1];
    float adi = ad_[i];
    float m = -1e30f;
    for (int j = start + lane; j < end; j += 64)
        m = fmaxf(m, leaky(as_[col[j]] + adi));
    for (int o = 32; o; o >>= 1) m = fmaxf(m, __shfl_xor(m, o));
    float den = 0.f;
    for (int j = start + lane; j < end; j += 64)
        den += __expf(leaky(as_[col[j]] + adi) - m);
    for (int o = 32; o; o >>= 1) den += __shfl_xor(den, o);
    float inv = 1.f / den;
    float acc[10];
#pragma unroll
    for (int k = 0; k < 10; k++) acc[k] = 0.f;
    for (int j = start; j < end; ++j) {
        int s = col[j];  // same for all lanes -> broadcast
        float alpha = __expf(leaky(as_[s] + adi) - m) * inv;
        const float* row = hW + (size_t)s * C_HID;
#pragma unroll
        for (int k = 0; k < 10; k++)
            acc[k] = fmaf(alpha, row[k * 64 + lane], acc[k]);
    }
#pragma unroll
    for (int k = 0; k < 10; k++) {
        float v = acc[k] + bias[k * 64 + lane];
        if (do_relu) v = fmaxf(v, 0.f);
        out[(size_t)i * C_HID + k * 64 + lane] = v;
    }
}

// ---------------- layer 5 (Co=2) ----------------
__global__ __launch_bounds__(256) void k_gemm2(const float* __restrict__ h,
                                               const float* __restrict__ W,
                                               float* __restrict__ hW5) {
    int wave = (blockIdx.x * blockDim.x + threadIdx.x) >> 6;
    int lane = threadIdx.x & 63;
    if (wave >= N_NODES) return;
    const float* row = h + (size_t)wave * C_HID;
    float a0 = 0.f, a1 = 0.f;
#pragma unroll
    for (int k = lane; k < C_HID; k += 64) {
        float v = row[k];
        a0 = fmaf(v, W[k * 2 + 0], a0);
        a1 = fmaf(v, W[k * 2 + 1], a1);
    }
    for (int o = 32; o; o >>= 1) { a0 += __shfl_xor(a0, o); a1 += __shfl_xor(a1, o); }
    if (lane == 0) { hW5[wave * 2 + 0] = a0; hW5[wave * 2 + 1] = a1; }
}

__global__ void k_logits2(const float* __restrict__ hW5, const float* __restrict__ asrc,
                          const float* __restrict__ adst,
                          float* __restrict__ as_, float* __restrict__ ad_) {
    int n = blockIdx.x * blockDim.x + threadIdx.x;
    if (n >= N_NODES) return;
    float h0 = hW5[n * 2], h1 = hW5[n * 2 + 1];
    as_[n] = h0 * asrc[0] + h1 * asrc[1];
    ad_[n] = h0 * adst[0] + h1 * adst[1];
}

__global__ void k_agg2(const float* __restrict__ hW5, const float* __restrict__ as_,
                       const float* __restrict__ ad_, const int* __restrict__ rowptr,
                       const int* __restrict__ col, const float* __restrict__ bias,
                       float* __restrict__ out) {
    int i = blockIdx.x * blockDim.x + threadIdx.x;
    if (i >= N_NODES) return;
    int start = rowptr[i], end = rowptr[i + 1];
    float adi = ad_[i];
    float m = -1e30f;
    for (int j = start; j < end; j++) m = fmaxf(m, leaky(as_[col[j]] + adi));
    float den = 0.f;
    for (int j = start; j < end; j++) den += __expf(leaky(as_[col[j]] + adi) - m);
    float inv = 1.f / den;
    float o0 = 0.f, o1 = 0.f;
    for (int j = start; j < end; j++) {
        int s = col[j];
        float al = __expf(leaky(as_[s] + adi) - m) * inv;
        o0 = fmaf(al, hW5[s * 2 + 0], o0);
        o1 = fmaf(al, hW5[s * 2 + 1], o1);
    }
    out[i * 2 + 0] = o0 + bias[0];
    out[i * 2 + 1] = o1 + bias[1];
}

extern "C" void kernel_launch(void* const* d_in, const int* in_sizes, int n_in,
                              void* d_out, int out_size, void* d_ws, size_t ws_size,
                              hipStream_t stream) {
    const float* x   = (const float*)d_in[0];
    const int*   ei  = (const int*)d_in[1];
    const float* W[5]  = {(const float*)d_in[2],  (const float*)d_in[6],
                          (const float*)d_in[10], (const float*)d_in[14],
                          (const float*)d_in[18]};
    const float* As[5] = {(const float*)d_in[3],  (const float*)d_in[7],
                          (const float*)d_in[11], (const float*)d_in[15],
                          (const float*)d_in[19]};
    const float* Ad[5] = {(const float*)d_in[4],  (const float*)d_in[8],
                          (const float*)d_in[12], (const float*)d_in[16],
                          (const float*)d_in[20]};
    const float* Bi[5] = {(const float*)d_in[5],  (const float*)d_in[9],
                          (const float*)d_in[13], (const float*)d_in[17],
                          (const float*)d_in[21]};
    float* out = (float*)d_out;

    // workspace layout
    float* bufX = (float*)d_ws;                       // N*640
    float* bufY = bufX + (size_t)N_NODES * C_HID;     // N*640
    float* as_  = bufY + (size_t)N_NODES * C_HID;     // N
    float* ad_  = as_ + N_NODES;                      // N
    float* hW5  = ad_ + N_NODES;                      // N*2
    int*  rowptr = (int*)(hW5 + (size_t)N_NODES * 2); // N+1
    int*  counts = rowptr + (N_NODES + 1);            // N (also cursor)
    int*  col    = counts + N_NODES;                  // ET

    const int TB = 256;
    // ---- CSR build (same every call; edges fixed across layers) ----
    k_zero<<<(N_NODES + TB - 1) / TB, TB, 0, stream>>>(counts, N_NODES);
    k_count<<<(ET + TB - 1) / TB, TB, 0, stream>>>(ei, counts);
    k_scan<<<1, 1024, 0, stream>>>(counts, rowptr);
    k_copy<<<(N_NODES + TB - 1) / TB, TB, 0, stream>>>(rowptr, counts, N_NODES);
    k_fill<<<(ET + TB - 1) / TB, TB, 0, stream>>>(ei, counts, col);

    dim3 gemmGrid((N_NODES + 63) / 64, C_HID / 64);
    int nodeWaveBlocks = (N_NODES + 3) / 4;  // 4 waves (nodes) per 256-thr block

    // ---- layer 1: x(128) -> bufX = hW1 -> bufY = h1 ----
    k_gemm<<<gemmGrid, TB, 0, stream>>>(x, W[0], bufX, N_NODES, 128, C_HID);
    k_logits<<<nodeWaveBlocks, TB, 0, stream>>>(bufX, As[0], Ad[0], as_, ad_);
    k_agg640<<<nodeWaveBlocks, TB, 0, stream>>>(bufX, as_, ad_, rowptr, col, Bi[0], bufY, 1);

    // ---- layers 2..4: bufY -> bufX(hW) -> bufY(h) ----
    for (int l = 1; l <= 3; ++l) {
        k_gemm<<<gemmGrid, TB, 0, stream>>>(bufY, W[l], bufX, N_NODES, C_HID, C_HID);
        k_logits<<<nodeWaveBlocks, TB, 0, stream>>>(bufX, As[l], Ad[l], as_, ad_);
        k_agg640<<<nodeWaveBlocks, TB, 0, stream>>>(bufX, as_, ad_, rowptr, col, Bi[l], bufY, 1);
    }

    // ---- layer 5: bufY -> hW5 (N,2) -> out ----
    k_gemm2<<<nodeWaveBlocks, TB, 0, stream>>>(bufY, W[4], hW5);
    k_logits2<<<(N_NODES + TB - 1) / TB, TB, 0, stream>>>(hW5, As[4], Ad[4], as_, ad_);
    k_agg2<<<(N_NODES + TB - 1) / TB, TB, 0, stream>>>(hW5, as_, ad_, rowptr, col, Bi[4], out);
}

// Round 2
// 1032.532 us; speedup vs baseline: 1.3943x; 1.3943x over previous
//
#include <hip/hip_runtime.h>
#include <math.h>

#define N_NODES 20000
#define MPAD 20096            // 157 * 128
#define E_EDGES 320000
#define ET (E_EDGES + N_NODES)   // edges incl. self-loops
#define C_HID 640
#define NEG_SLOPE 0.2f

typedef __attribute__((ext_vector_type(8))) short bf16x8;   // 8 bf16 in 4 VGPRs
typedef __attribute__((ext_vector_type(4))) float f32x4;

__device__ __forceinline__ float leaky(float x) { return x > 0.f ? x : NEG_SLOPE * x; }

// round-to-nearest-even fp32 -> bf16 bits (finite values only)
__device__ __forceinline__ unsigned short f2bf(float f) {
    unsigned u = __float_as_uint(f);
    unsigned r = (u + 0x7fffu + ((u >> 16) & 1u)) >> 16;
    return (unsigned short)r;
}
__device__ __forceinline__ float bf2f(unsigned short h) {
    return __uint_as_float(((unsigned)h) << 16);
}

__device__ __forceinline__ void gld16(const void* g, void* l) {
    __builtin_amdgcn_global_load_lds((const __attribute__((address_space(1))) unsigned int*)g,
                                     (__attribute__((address_space(3))) unsigned int*)l,
                                     16, 0, 0);
}

// ---------------- CSR build (by dst) ----------------
__global__ void k_zero(int* p, int n) {
    int i = blockIdx.x * blockDim.x + threadIdx.x;
    if (i < n) p[i] = 0;
}

__global__ void k_count(const int* __restrict__ ei, int* __restrict__ counts) {
    int j = blockIdx.x * blockDim.x + threadIdx.x;
    if (j >= ET) return;
    int d = (j < E_EDGES) ? ei[E_EDGES + j] : (j - E_EDGES);
    atomicAdd(&counts[d], 1);
}

__global__ void k_scan(const int* __restrict__ counts, int* __restrict__ rowptr) {
    __shared__ int buf[1024];
    __shared__ int carry;
    int t = threadIdx.x;
    if (t == 0) { carry = 0; rowptr[0] = 0; }
    __syncthreads();
    for (int base = 0; base < N_NODES; base += 1024) {
        int i = base + t;
        int v = (i < N_NODES) ? counts[i] : 0;
        buf[t] = v;
        __syncthreads();
        for (int off = 1; off < 1024; off <<= 1) {
            int x = (t >= off) ? buf[t - off] : 0;
            __syncthreads();
            buf[t] += x;
            __syncthreads();
        }
        int incl = buf[t] + carry;
        if (i < N_NODES) rowptr[i + 1] = incl;
        __syncthreads();
        if (t == 1023) carry = incl;
        __syncthreads();
    }
}

__global__ void k_copy(const int* __restrict__ a, int* __restrict__ b, int n) {
    int i = blockIdx.x * blockDim.x + threadIdx.x;
    if (i < n) b[i] = a[i];
}

__global__ void k_fill(const int* __restrict__ ei, int* __restrict__ cursor, int* __restrict__ col) {
    int j = blockIdx.x * blockDim.x + threadIdx.x;
    if (j >= ET) return;
    int s, d;
    if (j < E_EDGES) { s = ei[j]; d = ei[E_EDGES + j]; }
    else { s = d = j - E_EDGES; }
    int pos = atomicAdd(&cursor[d], 1);
    col[pos] = s;
}

// ---------------- split/convert helpers ----------------
// x [N,128] fp32 -> hi/lo bf16 [MPAD,128], pad rows zeroed
__global__ void k_splitx(const float* __restrict__ x, unsigned short* __restrict__ xh,
                         unsigned short* __restrict__ xl) {
    int idx = blockIdx.x * blockDim.x + threadIdx.x;   // one float4 per thread
    if (idx >= MPAD * 128 / 4) return;
    int row = idx >> 5;                                 // 32 float4 per row
    float4 v = make_float4(0.f, 0.f, 0.f, 0.f);
    if (row < N_NODES) v = ((const float4*)x)[idx];
    float a[4] = {v.x, v.y, v.z, v.w};
    unsigned short h[4], l[4];
#pragma unroll
    for (int i = 0; i < 4; i++) {
        h[i] = f2bf(a[i]);
        l[i] = f2bf(a[i] - bf2f(h[i]));
    }
    *(ushort4*)&xh[idx * 4] = make_ushort4(h[0], h[1], h[2], h[3]);
    *(ushort4*)&xl[idx * 4] = make_ushort4(l[0], l[1], l[2], l[3]);
}

// W [K,640] fp32 -> transposed hi/lo bf16 [640,K]
__global__ void k_splitW(const float* __restrict__ W, unsigned short* __restrict__ Wth,
                         unsigned short* __restrict__ Wtl, int K) {
    int idx = blockIdx.x * blockDim.x + threadIdx.x;
    if (idx >= K * C_HID) return;
    int k = idx / C_HID, n = idx - k * C_HID;
    float w = W[idx];
    unsigned short h = f2bf(w);
    Wth[n * K + k] = h;
    Wtl[n * K + k] = f2bf(w - bf2f(h));
}

// zero pad rows [N_NODES, MPAD) of the [MPAD,640] hi/lo pair
__global__ void k_padzero(unsigned short* __restrict__ ph, unsigned short* __restrict__ pl) {
    int idx = blockIdx.x * blockDim.x + threadIdx.x;
    int total = (MPAD - N_NODES) * C_HID;
    if (idx >= total) return;
    ph[N_NODES * C_HID + idx] = 0;
    pl[N_NODES * C_HID + idx] = 0;
}

// ---------------- split-bf16 MFMA GEMM: C[M,640] = A[MPAD,K] @ Wt[640,K]^T ----------------
// A given as hi/lo bf16, Wt as hi/lo bf16 (n-major). 128x128 tile, BK=32,
// 256 threads = 4 waves in 2x2, each wave 64x64 via 4x4 of 16x16x32 MFMA,
// 3 passes (hh, hl, lh) for ~fp32 accuracy. global_load_lds width-16 staging.
__global__ __launch_bounds__(256) void k_mfma_gemm(
    const unsigned short* __restrict__ Ahi, const unsigned short* __restrict__ Alo,
    const unsigned short* __restrict__ Bth, const unsigned short* __restrict__ Btl,
    float* __restrict__ C, int K, int M) {
    __shared__ unsigned short lds[4 * 128 * 32];   // Ahi | Alo | Bhi | Blo, 8KB each
    const int t = threadIdx.x;
    const int lane = t & 63, wv = t >> 6;
    const int wm = wv & 1, wn = wv >> 1;
    const int quad = lane >> 4, cl = lane & 15;
    const int rowBase = blockIdx.x * 128;
    const int colBase = blockIdx.y * 128;
    const int r = t >> 2, c8 = (t & 3) * 8;

    f32x4 acc[4][4];
#pragma unroll
    for (int i = 0; i < 4; i++)
#pragma unroll
        for (int j = 0; j < 4; j++)
            acc[i][j] = (f32x4){0.f, 0.f, 0.f, 0.f};

    for (int k0 = 0; k0 < K; k0 += 32) {
        __syncthreads();   // protect LDS from overwrite while prior iter still reads
#pragma unroll
        for (int p = 0; p < 2; ++p) {
            int row = p * 64 + r;
            size_t ga = (size_t)(rowBase + row) * K + k0 + c8;   // rows < MPAD (padded)
            size_t gb = (size_t)(colBase + row) * K + k0 + c8;   // rows < 640
            int lo = row * 32 + c8;                              // == p*4096B + t*16B
            gld16(Ahi + ga, &lds[lo]);
            gld16(Alo + ga, &lds[4096 + lo]);
            gld16(Bth + gb, &lds[8192 + lo]);
            gld16(Btl + gb, &lds[12288 + lo]);
        }
        __syncthreads();   // drains vmcnt for global_load_lds

        bf16x8 ah[4], al[4], bh[4], bl[4];
#pragma unroll
        for (int i = 0; i < 4; ++i) {
            int am = (wm * 64 + i * 16 + cl) * 32 + quad * 8;
            ah[i] = *(const bf16x8*)&lds[am];
            al[i] = *(const bf16x8*)&lds[4096 + am];
            int bn = (wn * 64 + i * 16 + cl) * 32 + quad * 8;
            bh[i] = *(const bf16x8*)&lds[8192 + bn];
            bl[i] = *(const bf16x8*)&lds[12288 + bn];
        }
#pragma unroll
        for (int i = 0; i < 4; ++i)
#pragma unroll
            for (int j = 0; j < 4; ++j) {
                acc[i][j] = __builtin_amdgcn_mfma_f32_16x16x32_bf16(ah[i], bh[j], acc[i][j], 0, 0, 0);
                acc[i][j] = __builtin_amdgcn_mfma_f32_16x16x32_bf16(ah[i], bl[j], acc[i][j], 0, 0, 0);
                acc[i][j] = __builtin_amdgcn_mfma_f32_16x16x32_bf16(al[i], bh[j], acc[i][j], 0, 0, 0);
            }
    }

    // C/D layout: col = lane&15, row = quad*4 + reg
#pragma unroll
    for (int i = 0; i < 4; ++i)
#pragma unroll
        for (int j = 0; j < 4; ++j) {
            int colC = colBase + wn * 64 + j * 16 + cl;
#pragma unroll
            for (int rr = 0; rr < 4; ++rr) {
                int rowC = rowBase + wm * 64 + i * 16 + quad * 4 + rr;
                if (rowC < M) C[(size_t)rowC * C_HID + colC] = acc[i][j][rr];
            }
        }
}

// ---------------- per-node attention logits (Co=640): wave per node ----------------
__global__ __launch_bounds__(256) void k_logits(const float* __restrict__ hW,
                                                const float* __restrict__ asrc,
                                                const float* __restrict__ adst,
                                                float* __restrict__ as_, float* __restrict__ ad_) {
    int wave = (blockIdx.x * blockDim.x + threadIdx.x) >> 6;
    int lane = threadIdx.x & 63;
    if (wave >= N_NODES) return;
    const float* row = hW + (size_t)wave * C_HID;
    float ps = 0.f, pd = 0.f;
#pragma unroll
    for (int k = lane; k < C_HID; k += 64) {
        float v = row[k];
        ps = fmaf(v, asrc[k], ps);
        pd = fmaf(v, adst[k], pd);
    }
    for (int o = 32; o; o >>= 1) { ps += __shfl_xor(ps, o); pd += __shfl_xor(pd, o); }
    if (lane == 0) { as_[wave] = ps; ad_[wave] = pd; }
}

// ---------------- softmax + weighted aggregation; writes bf16 hi/lo pair ----------------
__global__ __launch_bounds__(256) void k_agg640(const float* __restrict__ hW,
                                                const float* __restrict__ as_,
                                                const float* __restrict__ ad_,
                                                const int* __restrict__ rowptr,
                                                const int* __restrict__ col,
                                                const float* __restrict__ bias,
                                                unsigned short* __restrict__ outh,
                                                unsigned short* __restrict__ outl) {
    int wave = (blockIdx.x * blockDim.x + threadIdx.x) >> 6;
    int lane = threadIdx.x & 63;
    if (wave >= N_NODES) return;
    int i = wave;
    int start = rowptr[i], end = rowptr[i + 1];
    float adi = ad_[i];
    float m = -1e30f;
    for (int j = start + lane; j < end; j += 64)
        m = fmaxf(m, leaky(as_[col[j]] + adi));
    for (int o = 32; o; o >>= 1) m = fmaxf(m, __shfl_xor(m, o));
    float den = 0.f;
    for (int j = start + lane; j < end; j += 64)
        den += __expf(leaky(as_[col[j]] + adi) - m);
    for (int o = 32; o; o >>= 1) den += __shfl_xor(den, o);
    float inv = 1.f / den;
    float acc[10];
#pragma unroll
    for (int k = 0; k < 10; k++) acc[k] = 0.f;
    for (int j = start; j < end; ++j) {
        int s = col[j];  // uniform across wave -> broadcast
        float alpha = __expf(leaky(as_[s] + adi) - m) * inv;
        const float* row = hW + (size_t)s * C_HID;
#pragma unroll
        for (int k = 0; k < 10; k++)
            acc[k] = fmaf(alpha, row[k * 64 + lane], acc[k]);
    }
#pragma unroll
    for (int k = 0; k < 10; k++) {
        float v = fmaxf(acc[k] + bias[k * 64 + lane], 0.f);  // layers 1-4 all have ReLU
        unsigned short h = f2bf(v);
        outh[(size_t)i * C_HID + k * 64 + lane] = h;
        outl[(size_t)i * C_HID + k * 64 + lane] = f2bf(v - bf2f(h));
    }
}

// ---------------- layer 5 (Co=2) ----------------
__global__ __launch_bounds__(256) void k_gemm2(const unsigned short* __restrict__ hh,
                                               const unsigned short* __restrict__ hl,
                                               const float* __restrict__ W,
                                               float* __restrict__ hW5) {
    int wave = (blockIdx.x * blockDim.x + threadIdx.x) >> 6;
    int lane = threadIdx.x & 63;
    if (wave >= N_NODES) return;
    const unsigned short* rh = hh + (size_t)wave * C_HID;
    const unsigned short* rl = hl + (size_t)wave * C_HID;
    float a0 = 0.f, a1 = 0.f;
#pragma unroll
    for (int k = lane; k < C_HID; k += 64) {
        float v = bf2f(rh[k]) + bf2f(rl[k]);
        a0 = fmaf(v, W[k * 2 + 0], a0);
        a1 = fmaf(v, W[k * 2 + 1], a1);
    }
    for (int o = 32; o; o >>= 1) { a0 += __shfl_xor(a0, o); a1 += __shfl_xor(a1, o); }
    if (lane == 0) { hW5[wave * 2 + 0] = a0; hW5[wave * 2 + 1] = a1; }
}

__global__ void k_logits2(const float* __restrict__ hW5, const float* __restrict__ asrc,
                          const float* __restrict__ adst,
                          float* __restrict__ as_, float* __restrict__ ad_) {
    int n = blockIdx.x * blockDim.x + threadIdx.x;
    if (n >= N_NODES) return;
    float h0 = hW5[n * 2], h1 = hW5[n * 2 + 1];
    as_[n] = h0 * asrc[0] + h1 * asrc[1];
    ad_[n] = h0 * adst[0] + h1 * adst[1];
}

__global__ void k_agg2(const float* __restrict__ hW5, const float* __restrict__ as_,
                       const float* __restrict__ ad_, const int* __restrict__ rowptr,
                       const int* __restrict__ col, const float* __restrict__ bias,
                       float* __restrict__ out) {
    int i = blockIdx.x * blockDim.x + threadIdx.x;
    if (i >= N_NODES) return;
    int start = rowptr[i], end = rowptr[i + 1];
    float adi = ad_[i];
    float m = -1e30f;
    for (int j = start; j < end; j++) m = fmaxf(m, leaky(as_[col[j]] + adi));
    float den = 0.f;
    for (int j = start; j < end; j++) den += __expf(leaky(as_[col[j]] + adi) - m);
    float inv = 1.f / den;
    float o0 = 0.f, o1 = 0.f;
    for (int j = start; j < end; j++) {
        int s = col[j];
        float al = __expf(leaky(as_[s] + adi) - m) * inv;
        o0 = fmaf(al, hW5[s * 2 + 0], o0);
        o1 = fmaf(al, hW5[s * 2 + 1], o1);
    }
    out[i * 2 + 0] = o0 + bias[0];
    out[i * 2 + 1] = o1 + bias[1];
}

extern "C" void kernel_launch(void* const* d_in, const int* in_sizes, int n_in,
                              void* d_out, int out_size, void* d_ws, size_t ws_size,
                              hipStream_t stream) {
    const float* x   = (const float*)d_in[0];
    const int*   ei  = (const int*)d_in[1];
    const float* W[5]  = {(const float*)d_in[2],  (const float*)d_in[6],
                          (const float*)d_in[10], (const float*)d_in[14],
                          (const float*)d_in[18]};
    const float* As[5] = {(const float*)d_in[3],  (const float*)d_in[7],
                          (const float*)d_in[11], (const float*)d_in[15],
                          (const float*)d_in[19]};
    const float* Ad[5] = {(const float*)d_in[4],  (const float*)d_in[8],
                          (const float*)d_in[12], (const float*)d_in[16],
                          (const float*)d_in[20]};
    const float* Bi[5] = {(const float*)d_in[5],  (const float*)d_in[9],
                          (const float*)d_in[13], (const float*)d_in[17],
                          (const float*)d_in[21]};
    float* out = (float*)d_out;

    // workspace layout (~106.2 MB)
    char* w = (char*)d_ws;
    float* bufX = (float*)w;                 w += (size_t)N_NODES * C_HID * 4;   // hW fp32
    unsigned short* pair_hi = (unsigned short*)w; w += (size_t)MPAD * C_HID * 2; // h hi bf16
    unsigned short* pair_lo = (unsigned short*)w; w += (size_t)MPAD * C_HID * 2; // h lo bf16
    unsigned short* Wth = (unsigned short*)w;     w += (size_t)C_HID * C_HID * 2;
    unsigned short* Wtl = (unsigned short*)w;     w += (size_t)C_HID * C_HID * 2;
    float* as_  = (float*)w;  w += N_NODES * 4;
    float* ad_  = (float*)w;  w += N_NODES * 4;
    float* hW5  = (float*)w;  w += N_NODES * 2 * 4;
    int* rowptr = (int*)w;    w += (N_NODES + 1) * 4 + 12;   // pad to 16B
    int* counts = (int*)w;    w += N_NODES * 4;
    int* col    = (int*)w;    w += ET * 4;

    const int TB = 256;
    // ---- CSR build ----
    k_zero<<<(N_NODES + TB - 1) / TB, TB, 0, stream>>>(counts, N_NODES);
    k_count<<<(ET + TB - 1) / TB, TB, 0, stream>>>(ei, counts);
    k_scan<<<1, 1024, 0, stream>>>(counts, rowptr);
    k_copy<<<(N_NODES + TB - 1) / TB, TB, 0, stream>>>(rowptr, counts, N_NODES);
    k_fill<<<(ET + TB - 1) / TB, TB, 0, stream>>>(ei, counts, col);

    // ---- pad-row zeroing + x split (x pair aliases the start of pair_hi/pair_lo) ----
    k_padzero<<<((MPAD - N_NODES) * C_HID + TB - 1) / TB, TB, 0, stream>>>(pair_hi, pair_lo);
    k_splitx<<<(MPAD * 128 / 4 + TB - 1) / TB, TB, 0, stream>>>(x, pair_hi, pair_lo);

    dim3 gemmGrid(MPAD / 128, C_HID / 128);   // 157 x 5
    int nodeWaveBlocks = (N_NODES + 3) / 4;

    // ---- layer 1 (K=128): xpair -> bufX -> pair ----
    k_splitW<<<(128 * C_HID + TB - 1) / TB, TB, 0, stream>>>(W[0], Wth, Wtl, 128);
    k_mfma_gemm<<<gemmGrid, TB, 0, stream>>>(pair_hi, pair_lo, Wth, Wtl, bufX, 128, N_NODES);
    k_logits<<<nodeWaveBlocks, TB, 0, stream>>>(bufX, As[0], Ad[0], as_, ad_);
    k_agg640<<<nodeWaveBlocks, TB, 0, stream>>>(bufX, as_, ad_, rowptr, col, Bi[0], pair_hi, pair_lo);

    // ---- layers 2..4 (K=640): pair -> bufX -> pair ----
    for (int l = 1; l <= 3; ++l) {
        k_splitW<<<(C_HID * C_HID + TB - 1) / TB, TB, 0, stream>>>(W[l], Wth, Wtl, C_HID);
        k_mfma_gemm<<<gemmGrid, TB, 0, stream>>>(pair_hi, pair_lo, Wth, Wtl, bufX, C_HID, N_NODES);
        k_logits<<<nodeWaveBlocks, TB, 0, stream>>>(bufX, As[l], Ad[l], as_, ad_);
        k_agg640<<<nodeWaveBlocks, TB, 0, stream>>>(bufX, as_, ad_, rowptr, col, Bi[l], pair_hi, pair_lo);
    }

    // ---- layer 5: pair -> hW5 (N,2) -> out ----
    k_gemm2<<<nodeWaveBlocks, TB, 0, stream>>>(pair_hi, pair_lo, W[4], hW5);
    k_logits2<<<(N_NODES + TB - 1) / TB, TB, 0, stream>>>(hW5, As[4], Ad[4], as_, ad_);
    k_agg2<<<(N_NODES + TB - 1) / TB, TB, 0, stream>>>(hW5, as_, ad_, rowptr, col, Bi[4], out);
}

// Round 3
// 927.074 us; speedup vs baseline: 1.5529x; 1.1138x over previous
//
#include <hip/hip_runtime.h>
#include <math.h>

#define N_NODES 20000
#define MPAD 20096            // 157 * 128
#define E_EDGES 320000
#define ET (E_EDGES + N_NODES)   // edges incl. self-loops
#define C_HID 640
#define NEG_SLOPE 0.2f

typedef __attribute__((ext_vector_type(8))) short bf16x8;   // 8 bf16 in 4 VGPRs
typedef __attribute__((ext_vector_type(4))) float f32x4;

__device__ __forceinline__ float leaky(float x) { return x > 0.f ? x : NEG_SLOPE * x; }

__device__ __forceinline__ unsigned short f2bf(float f) {
    unsigned u = __float_as_uint(f);
    unsigned r = (u + 0x7fffu + ((u >> 16) & 1u)) >> 16;
    return (unsigned short)r;
}
__device__ __forceinline__ float bf2f(unsigned short h) {
    return __uint_as_float(((unsigned)h) << 16);
}

__device__ __forceinline__ void gld16(const void* g, void* l) {
    __builtin_amdgcn_global_load_lds((const __attribute__((address_space(1))) unsigned int*)g,
                                     (__attribute__((address_space(3))) unsigned int*)l,
                                     16, 0, 0);
}

// ---------------- CSR build (by dst) ----------------
__global__ void k_zero(int* p, int n) {
    int i = blockIdx.x * blockDim.x + threadIdx.x;
    if (i < n) p[i] = 0;
}

__global__ void k_zerof(float* p, int n) {
    int i = blockIdx.x * blockDim.x + threadIdx.x;
    if (i < n) p[i] = 0.f;
}

__global__ void k_count(const int* __restrict__ ei, int* __restrict__ counts) {
    int j = blockIdx.x * blockDim.x + threadIdx.x;
    if (j >= ET) return;
    int d = (j < E_EDGES) ? ei[E_EDGES + j] : (j - E_EDGES);
    atomicAdd(&counts[d], 1);
}

// single-block scan: 1024 threads x 20 elems serial + Hillis-Steele on partials
__global__ __launch_bounds__(1024) void k_scan(const int* __restrict__ counts,
                                               int* __restrict__ rowptr) {
    __shared__ int part[1024];
    int t = threadIdx.x;
    int base = t * 20;
    int incl[20];
    int s = 0;
#pragma unroll
    for (int k = 0; k < 20; k++) {
        int i = base + k;
        int v = (i < N_NODES) ? counts[i] : 0;
        s += v;
        incl[k] = s;
    }
    part[t] = s;
    __syncthreads();
    for (int off = 1; off < 1024; off <<= 1) {
        int x = (t >= off) ? part[t - off] : 0;
        __syncthreads();
        part[t] += x;
        __syncthreads();
    }
    int prefix = (t == 0) ? 0 : part[t - 1];
    if (t == 0) rowptr[0] = 0;
#pragma unroll
    for (int k = 0; k < 20; k++) {
        int i = base + k;
        if (i < N_NODES) rowptr[i + 1] = prefix + incl[k];
    }
}

__global__ void k_copy(const int* __restrict__ a, int* __restrict__ b, int n) {
    int i = blockIdx.x * blockDim.x + threadIdx.x;
    if (i < n) b[i] = a[i];
}

__global__ void k_fill(const int* __restrict__ ei, int* __restrict__ cursor, int* __restrict__ col) {
    int j = blockIdx.x * blockDim.x + threadIdx.x;
    if (j >= ET) return;
    int s, d;
    if (j < E_EDGES) { s = ei[j]; d = ei[E_EDGES + j]; }
    else { s = d = j - E_EDGES; }
    int pos = atomicAdd(&cursor[d], 1);
    col[pos] = s;
}

// ---------------- split/convert helpers ----------------
__global__ void k_splitx(const float* __restrict__ x, unsigned short* __restrict__ xh,
                         unsigned short* __restrict__ xl) {
    int idx = blockIdx.x * blockDim.x + threadIdx.x;
    if (idx >= MPAD * 128 / 4) return;
    int row = idx >> 5;
    float4 v = make_float4(0.f, 0.f, 0.f, 0.f);
    if (row < N_NODES) v = ((const float4*)x)[idx];
    float a[4] = {v.x, v.y, v.z, v.w};
    unsigned short h[4], l[4];
#pragma unroll
    for (int i = 0; i < 4; i++) {
        h[i] = f2bf(a[i]);
        l[i] = f2bf(a[i] - bf2f(h[i]));
    }
    *(ushort4*)&xh[idx * 4] = make_ushort4(h[0], h[1], h[2], h[3]);
    *(ushort4*)&xl[idx * 4] = make_ushort4(l[0], l[1], l[2], l[3]);
}

__global__ void k_splitW(const float* __restrict__ W, unsigned short* __restrict__ Wth,
                         unsigned short* __restrict__ Wtl, int K) {
    int idx = blockIdx.x * blockDim.x + threadIdx.x;
    if (idx >= K * C_HID) return;
    int k = idx / C_HID, n = idx - k * C_HID;
    float w = W[idx];
    unsigned short h = f2bf(w);
    Wth[n * K + k] = h;
    Wtl[n * K + k] = f2bf(w - bf2f(h));
}

__global__ void k_padzero(unsigned short* __restrict__ ph, unsigned short* __restrict__ pl) {
    int idx = blockIdx.x * blockDim.x + threadIdx.x;
    int total = (MPAD - N_NODES) * C_HID;
    if (idx >= total) return;
    ph[N_NODES * C_HID + idx] = 0;
    pl[N_NODES * C_HID + idx] = 0;
}

// ---------------- split-bf16 MFMA GEMM + fused logits epilogue ----------------
// C[M,640] = A[MPAD,K] @ Wt[640,K]^T ; also as_[r] += C[r,:]·asrc, ad_[r] += C[r,:]·adst
__global__ __launch_bounds__(256) void k_mfma_gemm(
    const unsigned short* __restrict__ Ahi, const unsigned short* __restrict__ Alo,
    const unsigned short* __restrict__ Bth, const unsigned short* __restrict__ Btl,
    float* __restrict__ C, int K, int M,
    const float* __restrict__ asrc, const float* __restrict__ adst,
    float* __restrict__ as_, float* __restrict__ ad_) {
    __shared__ unsigned short lds[4 * 128 * 32];   // Ahi | Alo | Bhi | Blo, 8KB each
    const int t = threadIdx.x;
    const int lane = t & 63, wv = t >> 6;
    const int wm = wv & 1, wn = wv >> 1;
    const int quad = lane >> 4, cl = lane & 15;
    const int rowBase = blockIdx.x * 128;
    const int colBase = blockIdx.y * 128;
    const int r = t >> 2, c8 = (t & 3) * 8;

    f32x4 acc[4][4];
#pragma unroll
    for (int i = 0; i < 4; i++)
#pragma unroll
        for (int j = 0; j < 4; j++)
            acc[i][j] = (f32x4){0.f, 0.f, 0.f, 0.f};

    for (int k0 = 0; k0 < K; k0 += 32) {
        __syncthreads();
#pragma unroll
        for (int p = 0; p < 2; ++p) {
            int row = p * 64 + r;
            size_t ga = (size_t)(rowBase + row) * K + k0 + c8;
            size_t gb = (size_t)(colBase + row) * K + k0 + c8;
            int lo = row * 32 + c8;
            gld16(Ahi + ga, &lds[lo]);
            gld16(Alo + ga, &lds[4096 + lo]);
            gld16(Bth + gb, &lds[8192 + lo]);
            gld16(Btl + gb, &lds[12288 + lo]);
        }
        __syncthreads();

        bf16x8 ah[4], al[4], bh[4], bl[4];
#pragma unroll
        for (int i = 0; i < 4; ++i) {
            int am = (wm * 64 + i * 16 + cl) * 32 + quad * 8;
            ah[i] = *(const bf16x8*)&lds[am];
            al[i] = *(const bf16x8*)&lds[4096 + am];
            int bn = (wn * 64 + i * 16 + cl) * 32 + quad * 8;
            bh[i] = *(const bf16x8*)&lds[8192 + bn];
            bl[i] = *(const bf16x8*)&lds[12288 + bn];
        }
#pragma unroll
        for (int i = 0; i < 4; ++i)
#pragma unroll
            for (int j = 0; j < 4; ++j) {
                acc[i][j] = __builtin_amdgcn_mfma_f32_16x16x32_bf16(ah[i], bh[j], acc[i][j], 0, 0, 0);
                acc[i][j] = __builtin_amdgcn_mfma_f32_16x16x32_bf16(ah[i], bl[j], acc[i][j], 0, 0, 0);
                acc[i][j] = __builtin_amdgcn_mfma_f32_16x16x32_bf16(al[i], bh[j], acc[i][j], 0, 0, 0);
            }
    }

    // C stores; C/D layout: col = lane&15, row = quad*4 + reg
#pragma unroll
    for (int i = 0; i < 4; ++i)
#pragma unroll
        for (int j = 0; j < 4; ++j) {
            int colC = colBase + wn * 64 + j * 16 + cl;
#pragma unroll
            for (int rr = 0; rr < 4; ++rr) {
                int rowC = rowBase + wm * 64 + i * 16 + quad * 4 + rr;
                if (rowC < M) C[(size_t)rowC * C_HID + colC] = acc[i][j][rr];
            }
        }

    // fused logits: partial row-dots with asrc/adst, cl-shuffle reduce, atomic accumulate
    float av[4], dv[4];
#pragma unroll
    for (int j = 0; j < 4; ++j) {
        int cn = colBase + wn * 64 + j * 16 + cl;
        av[j] = asrc[cn];
        dv[j] = adst[cn];
    }
#pragma unroll
    for (int i = 0; i < 4; ++i)
#pragma unroll
        for (int rr = 0; rr < 4; ++rr) {
            float s = 0.f, d = 0.f;
#pragma unroll
            for (int j = 0; j < 4; ++j) {
                float v = acc[i][j][rr];
                s = fmaf(v, av[j], s);
                d = fmaf(v, dv[j], d);
            }
#pragma unroll
            for (int o = 8; o >= 1; o >>= 1) {   // reduce over cl (lane bits 0-3)
                s += __shfl_xor(s, o);
                d += __shfl_xor(d, o);
            }
            int rowC = rowBase + wm * 64 + i * 16 + quad * 4 + rr;
            if (cl == 0 && rowC < M) {
                atomicAdd(&as_[rowC], s);
                atomicAdd(&ad_[rowC], d);
            }
        }
}

// ---------------- per-edge softmax weights: wave per dst node ----------------
__global__ __launch_bounds__(256) void k_alpha(const float* __restrict__ as_,
                                               const float* __restrict__ ad_,
                                               const int* __restrict__ rowptr,
                                               const int* __restrict__ col,
                                               float* __restrict__ alpha) {
    int wave = (blockIdx.x * blockDim.x + threadIdx.x) >> 6;
    int lane = threadIdx.x & 63;
    if (wave >= N_NODES) return;
    int start = rowptr[wave], end = rowptr[wave + 1];
    float adi = ad_[wave];
    float m = -1e30f;
    for (int j = start + lane; j < end; j += 64)
        m = fmaxf(m, leaky(as_[col[j]] + adi));
    for (int o = 32; o; o >>= 1) m = fmaxf(m, __shfl_xor(m, o));
    float den = 0.f;
    for (int j = start + lane; j < end; j += 64)
        den += __expf(leaky(as_[col[j]] + adi) - m);
    for (int o = 32; o; o >>= 1) den += __shfl_xor(den, o);
    float inv = 1.f / den;
    for (int j = start + lane; j < end; j += 64)
        alpha[j] = __expf(leaky(as_[col[j]] + adi) - m) * inv;
}

// ---------------- weighted gather: wave = (node, 128-col chunk) ----------------
// grid (N/4, 5), block 256 = 4 waves (4 consecutive nodes), chunk = blockIdx.y
__global__ __launch_bounds__(256) void k_gather(const float* __restrict__ hW,
                                                const float* __restrict__ alpha,
                                                const int* __restrict__ rowptr,
                                                const int* __restrict__ col,
                                                const float* __restrict__ bias,
                                                unsigned short* __restrict__ outh,
                                                unsigned short* __restrict__ outl) {
    int wv = threadIdx.x >> 6, lane = threadIdx.x & 63;
    int node = blockIdx.x * 4 + wv;
    int c = blockIdx.y;
    if (node >= N_NODES) return;
    int start = rowptr[node], end = rowptr[node + 1];
    const float* base = hW + c * 128 + lane * 2;
    float ax = 0.f, ay = 0.f;
    int j = start;
    for (; j + 4 <= end; j += 4) {
        int s0 = col[j], s1 = col[j + 1], s2 = col[j + 2], s3 = col[j + 3];
        float a0 = alpha[j], a1 = alpha[j + 1], a2 = alpha[j + 2], a3 = alpha[j + 3];
        float2 r0 = *(const float2*)(base + (size_t)s0 * C_HID);
        float2 r1 = *(const float2*)(base + (size_t)s1 * C_HID);
        float2 r2 = *(const float2*)(base + (size_t)s2 * C_HID);
        float2 r3 = *(const float2*)(base + (size_t)s3 * C_HID);
        ax = fmaf(a0, r0.x, ax); ay = fmaf(a0, r0.y, ay);
        ax = fmaf(a1, r1.x, ax); ay = fmaf(a1, r1.y, ay);
        ax = fmaf(a2, r2.x, ax); ay = fmaf(a2, r2.y, ay);
        ax = fmaf(a3, r3.x, ax); ay = fmaf(a3, r3.y, ay);
    }
    for (; j < end; ++j) {
        int s = col[j];
        float a = alpha[j];
        float2 r = *(const float2*)(base + (size_t)s * C_HID);
        ax = fmaf(a, r.x, ax); ay = fmaf(a, r.y, ay);
    }
    float2 b = *(const float2*)&bias[c * 128 + lane * 2];
    float v0 = fmaxf(ax + b.x, 0.f);   // layers 1-4 all have ReLU
    float v1 = fmaxf(ay + b.y, 0.f);
    unsigned short h0 = f2bf(v0), h1 = f2bf(v1);
    size_t o = (size_t)node * C_HID + c * 128 + lane * 2;
    *(ushort2*)&outh[o] = make_ushort2(h0, h1);
    *(ushort2*)&outl[o] = make_ushort2(f2bf(v0 - bf2f(h0)), f2bf(v1 - bf2f(h1)));
}

// ---------------- layer 5 (Co=2) ----------------
__global__ __launch_bounds__(256) void k_gemm2(const unsigned short* __restrict__ hh,
                                               const unsigned short* __restrict__ hl,
                                               const float* __restrict__ W,
                                               float* __restrict__ hW5) {
    int wave = (blockIdx.x * blockDim.x + threadIdx.x) >> 6;
    int lane = threadIdx.x & 63;
    if (wave >= N_NODES) return;
    const unsigned short* rh = hh + (size_t)wave * C_HID;
    const unsigned short* rl = hl + (size_t)wave * C_HID;
    float a0 = 0.f, a1 = 0.f;
#pragma unroll
    for (int k = lane; k < C_HID; k += 64) {
        float v = bf2f(rh[k]) + bf2f(rl[k]);
        a0 = fmaf(v, W[k * 2 + 0], a0);
        a1 = fmaf(v, W[k * 2 + 1], a1);
    }
    for (int o = 32; o; o >>= 1) { a0 += __shfl_xor(a0, o); a1 += __shfl_xor(a1, o); }
    if (lane == 0) { hW5[wave * 2 + 0] = a0; hW5[wave * 2 + 1] = a1; }
}

__global__ void k_logits2(const float* __restrict__ hW5, const float* __restrict__ asrc,
                          const float* __restrict__ adst,
                          float* __restrict__ as_, float* __restrict__ ad_) {
    int n = blockIdx.x * blockDim.x + threadIdx.x;
    if (n >= N_NODES) return;
    float h0 = hW5[n * 2], h1 = hW5[n * 2 + 1];
    as_[n] = h0 * asrc[0] + h1 * asrc[1];
    ad_[n] = h0 * adst[0] + h1 * adst[1];
}

__global__ void k_agg2(const float* __restrict__ hW5, const float* __restrict__ as_,
                       const float* __restrict__ ad_, const int* __restrict__ rowptr,
                       const int* __restrict__ col, const float* __restrict__ bias,
                       float* __restrict__ out) {
    int i = blockIdx.x * blockDim.x + threadIdx.x;
    if (i >= N_NODES) return;
    int start = rowptr[i], end = rowptr[i + 1];
    float adi = ad_[i];
    float m = -1e30f;
    for (int j = start; j < end; j++) m = fmaxf(m, leaky(as_[col[j]] + adi));
    float den = 0.f;
    for (int j = start; j < end; j++) den += __expf(leaky(as_[col[j]] + adi) - m);
    float inv = 1.f / den;
    float o0 = 0.f, o1 = 0.f;
    for (int j = start; j < end; j++) {
        int s = col[j];
        float al = __expf(leaky(as_[s] + adi) - m) * inv;
        o0 = fmaf(al, hW5[s * 2 + 0], o0);
        o1 = fmaf(al, hW5[s * 2 + 1], o1);
    }
    out[i * 2 + 0] = o0 + bias[0];
    out[i * 2 + 1] = o1 + bias[1];
}

extern "C" void kernel_launch(void* const* d_in, const int* in_sizes, int n_in,
                              void* d_out, int out_size, void* d_ws, size_t ws_size,
                              hipStream_t stream) {
    const float* x   = (const float*)d_in[0];
    const int*   ei  = (const int*)d_in[1];
    const float* W[5]  = {(const float*)d_in[2],  (const float*)d_in[6],
                          (const float*)d_in[10], (const float*)d_in[14],
                          (const float*)d_in[18]};
    const float* As[5] = {(const float*)d_in[3],  (const float*)d_in[7],
                          (const float*)d_in[11], (const float*)d_in[15],
                          (const float*)d_in[19]};
    const float* Ad[5] = {(const float*)d_in[4],  (const float*)d_in[8],
                          (const float*)d_in[12], (const float*)d_in[16],
                          (const float*)d_in[20]};
    const float* Bi[5] = {(const float*)d_in[5],  (const float*)d_in[9],
                          (const float*)d_in[13], (const float*)d_in[17],
                          (const float*)d_in[21]};
    float* out = (float*)d_out;

    // workspace layout (~108 MB)
    char* w = (char*)d_ws;
    float* bufX = (float*)w;                 w += (size_t)N_NODES * C_HID * 4;   // hW fp32
    unsigned short* pair_hi = (unsigned short*)w; w += (size_t)MPAD * C_HID * 2;
    unsigned short* pair_lo = (unsigned short*)w; w += (size_t)MPAD * C_HID * 2;
    unsigned short* Wth = (unsigned short*)w;     w += (size_t)C_HID * C_HID * 2;
    unsigned short* Wtl = (unsigned short*)w;     w += (size_t)C_HID * C_HID * 2;
    float* as_  = (float*)w;  w += N_NODES * 4;
    float* ad_  = (float*)w;  w += N_NODES * 4;   // contiguous after as_
    float* hW5  = (float*)w;  w += N_NODES * 2 * 4;
    float* alpha = (float*)w; w += ET * 4;
    int* rowptr = (int*)w;    w += (N_NODES + 1) * 4 + 12;
    int* counts = (int*)w;    w += N_NODES * 4;
    int* col    = (int*)w;    w += ET * 4;

    const int TB = 256;
    // ---- CSR build ----
    k_zero<<<(N_NODES + TB - 1) / TB, TB, 0, stream>>>(counts, N_NODES);
    k_count<<<(ET + TB - 1) / TB, TB, 0, stream>>>(ei, counts);
    k_scan<<<1, 1024, 0, stream>>>(counts, rowptr);
    k_copy<<<(N_NODES + TB - 1) / TB, TB, 0, stream>>>(rowptr, counts, N_NODES);
    k_fill<<<(ET + TB - 1) / TB, TB, 0, stream>>>(ei, counts, col);

    k_padzero<<<((MPAD - N_NODES) * C_HID + TB - 1) / TB, TB, 0, stream>>>(pair_hi, pair_lo);
    k_splitx<<<(MPAD * 128 / 4 + TB - 1) / TB, TB, 0, stream>>>(x, pair_hi, pair_lo);

    dim3 gemmGrid(MPAD / 128, C_HID / 128);   // 157 x 5
    dim3 gathGrid(N_NODES / 4, 5);            // 5000 x 5
    int nodeWaveBlocks = (N_NODES + 3) / 4;

    for (int l = 0; l <= 3; ++l) {
        int K = (l == 0) ? 128 : C_HID;
        k_zerof<<<(2 * N_NODES + TB - 1) / TB, TB, 0, stream>>>(as_, 2 * N_NODES);
        k_splitW<<<(K * C_HID + TB - 1) / TB, TB, 0, stream>>>(W[l], Wth, Wtl, K);
        k_mfma_gemm<<<gemmGrid, TB, 0, stream>>>(pair_hi, pair_lo, Wth, Wtl, bufX, K, N_NODES,
                                                 As[l], Ad[l], as_, ad_);
        k_alpha<<<nodeWaveBlocks, TB, 0, stream>>>(as_, ad_, rowptr, col, alpha);
        k_gather<<<gathGrid, TB, 0, stream>>>(bufX, alpha, rowptr, col, Bi[l], pair_hi, pair_lo);
    }

    // ---- layer 5: pair -> hW5 (N,2) -> out ----
    k_gemm2<<<nodeWaveBlocks, TB, 0, stream>>>(pair_hi, pair_lo, W[4], hW5);
    k_logits2<<<(N_NODES + TB - 1) / TB, TB, 0, stream>>>(hW5, As[4], Ad[4], as_, ad_);
    k_agg2<<<(N_NODES + TB - 1) / TB, TB, 0, stream>>>(hW5, as_, ad_, rowptr, col, Bi[4], out);
}

// Round 4
// 881.075 us; speedup vs baseline: 1.6340x; 1.0522x over previous
//
#include <hip/hip_runtime.h>
#include <math.h>

#define N_NODES 20000
#define MPAD 20096            // 157 * 128
#define E_EDGES 320000
#define ET (E_EDGES + N_NODES)   // edges incl. self-loops
#define C_HID 640
#define NEG_SLOPE 0.2f

typedef __attribute__((ext_vector_type(8))) short bf16x8;   // 8 bf16 in 4 VGPRs
typedef __attribute__((ext_vector_type(4))) float f32x4;

__device__ __forceinline__ float leaky(float x) { return x > 0.f ? x : NEG_SLOPE * x; }

__device__ __forceinline__ unsigned short f2bf(float f) {
    unsigned u = __float_as_uint(f);
    unsigned r = (u + 0x7fffu + ((u >> 16) & 1u)) >> 16;
    return (unsigned short)r;
}
__device__ __forceinline__ float bf2f(unsigned short h) {
    return __uint_as_float(((unsigned)h) << 16);
}

__device__ __forceinline__ void gld16(const void* g, void* l) {
    __builtin_amdgcn_global_load_lds((const __attribute__((address_space(1))) unsigned int*)g,
                                     (__attribute__((address_space(3))) unsigned int*)l,
                                     16, 0, 0);
}

// ---------------- CSR build (by dst) ----------------
__global__ void k_zero(int* p, int n) {
    int i = blockIdx.x * blockDim.x + threadIdx.x;
    if (i < n) p[i] = 0;
}

__global__ void k_zerof(float* p, int n) {
    int i = blockIdx.x * blockDim.x + threadIdx.x;
    if (i < n) p[i] = 0.f;
}

__global__ void k_count(const int* __restrict__ ei, int* __restrict__ counts) {
    int j = blockIdx.x * blockDim.x + threadIdx.x;
    if (j >= ET) return;
    int d = (j < E_EDGES) ? ei[E_EDGES + j] : (j - E_EDGES);
    atomicAdd(&counts[d], 1);
}

// single-block scan: 1024 threads x 20 elems serial + Hillis-Steele on partials
__global__ __launch_bounds__(1024) void k_scan(const int* __restrict__ counts,
                                               int* __restrict__ rowptr) {
    __shared__ int part[1024];
    int t = threadIdx.x;
    int base = t * 20;
    int incl[20];
    int s = 0;
#pragma unroll
    for (int k = 0; k < 20; k++) {
        int i = base + k;
        int v = (i < N_NODES) ? counts[i] : 0;
        s += v;
        incl[k] = s;
    }
    part[t] = s;
    __syncthreads();
    for (int off = 1; off < 1024; off <<= 1) {
        int x = (t >= off) ? part[t - off] : 0;
        __syncthreads();
        part[t] += x;
        __syncthreads();
    }
    int prefix = (t == 0) ? 0 : part[t - 1];
    if (t == 0) rowptr[0] = 0;
#pragma unroll
    for (int k = 0; k < 20; k++) {
        int i = base + k;
        if (i < N_NODES) rowptr[i + 1] = prefix + incl[k];
    }
}

__global__ void k_copy(const int* __restrict__ a, int* __restrict__ b, int n) {
    int i = blockIdx.x * blockDim.x + threadIdx.x;
    if (i < n) b[i] = a[i];
}

__global__ void k_fill(const int* __restrict__ ei, int* __restrict__ cursor, int* __restrict__ col) {
    int j = blockIdx.x * blockDim.x + threadIdx.x;
    if (j >= ET) return;
    int s, d;
    if (j < E_EDGES) { s = ei[j]; d = ei[E_EDGES + j]; }
    else { s = d = j - E_EDGES; }
    int pos = atomicAdd(&cursor[d], 1);
    col[pos] = s;
}

// ---------------- split/convert helpers ----------------
__global__ void k_splitx(const float* __restrict__ x, unsigned short* __restrict__ xh,
                         unsigned short* __restrict__ xl) {
    int idx = blockIdx.x * blockDim.x + threadIdx.x;
    if (idx >= MPAD * 128 / 4) return;
    int row = idx >> 5;
    float4 v = make_float4(0.f, 0.f, 0.f, 0.f);
    if (row < N_NODES) v = ((const float4*)x)[idx];
    float a[4] = {v.x, v.y, v.z, v.w};
    unsigned short h[4], l[4];
#pragma unroll
    for (int i = 0; i < 4; i++) {
        h[i] = f2bf(a[i]);
        l[i] = f2bf(a[i] - bf2f(h[i]));
    }
    *(ushort4*)&xh[idx * 4] = make_ushort4(h[0], h[1], h[2], h[3]);
    *(ushort4*)&xl[idx * 4] = make_ushort4(l[0], l[1], l[2], l[3]);
}

__global__ void k_splitW(const float* __restrict__ W, unsigned short* __restrict__ Wth,
                         unsigned short* __restrict__ Wtl, int K) {
    int idx = blockIdx.x * blockDim.x + threadIdx.x;
    if (idx >= K * C_HID) return;
    int k = idx / C_HID, n = idx - k * C_HID;
    float w = W[idx];
    unsigned short h = f2bf(w);
    Wth[n * K + k] = h;
    Wtl[n * K + k] = f2bf(w - bf2f(h));
}

__global__ void k_padzero(unsigned short* __restrict__ ph, unsigned short* __restrict__ pl) {
    int idx = blockIdx.x * blockDim.x + threadIdx.x;
    int total = (MPAD - N_NODES) * C_HID;
    if (idx >= total) return;
    ph[N_NODES * C_HID + idx] = 0;
    pl[N_NODES * C_HID + idx] = 0;
}

// ---------------- split-bf16 MFMA GEMM + fused logits epilogue ----------------
__global__ __launch_bounds__(256) void k_mfma_gemm(
    const unsigned short* __restrict__ Ahi, const unsigned short* __restrict__ Alo,
    const unsigned short* __restrict__ Bth, const unsigned short* __restrict__ Btl,
    float* __restrict__ C, int K, int M,
    const float* __restrict__ asrc, const float* __restrict__ adst,
    float* __restrict__ as_, float* __restrict__ ad_) {
    __shared__ unsigned short lds[4 * 128 * 32];   // Ahi | Alo | Bhi | Blo, 8KB each
    const int t = threadIdx.x;
    const int lane = t & 63, wv = t >> 6;
    const int wm = wv & 1, wn = wv >> 1;
    const int quad = lane >> 4, cl = lane & 15;
    const int rowBase = blockIdx.x * 128;
    const int colBase = blockIdx.y * 128;
    const int r = t >> 2, c8 = (t & 3) * 8;

    f32x4 acc[4][4];
#pragma unroll
    for (int i = 0; i < 4; i++)
#pragma unroll
        for (int j = 0; j < 4; j++)
            acc[i][j] = (f32x4){0.f, 0.f, 0.f, 0.f};

    for (int k0 = 0; k0 < K; k0 += 32) {
        __syncthreads();
#pragma unroll
        for (int p = 0; p < 2; ++p) {
            int row = p * 64 + r;
            size_t ga = (size_t)(rowBase + row) * K + k0 + c8;
            size_t gb = (size_t)(colBase + row) * K + k0 + c8;
            int lo = row * 32 + c8;
            gld16(Ahi + ga, &lds[lo]);
            gld16(Alo + ga, &lds[4096 + lo]);
            gld16(Bth + gb, &lds[8192 + lo]);
            gld16(Btl + gb, &lds[12288 + lo]);
        }
        __syncthreads();

        bf16x8 ah[4], al[4], bh[4], bl[4];
#pragma unroll
        for (int i = 0; i < 4; ++i) {
            int am = (wm * 64 + i * 16 + cl) * 32 + quad * 8;
            ah[i] = *(const bf16x8*)&lds[am];
            al[i] = *(const bf16x8*)&lds[4096 + am];
            int bn = (wn * 64 + i * 16 + cl) * 32 + quad * 8;
            bh[i] = *(const bf16x8*)&lds[8192 + bn];
            bl[i] = *(const bf16x8*)&lds[12288 + bn];
        }
#pragma unroll
        for (int i = 0; i < 4; ++i)
#pragma unroll
            for (int j = 0; j < 4; ++j) {
                acc[i][j] = __builtin_amdgcn_mfma_f32_16x16x32_bf16(ah[i], bh[j], acc[i][j], 0, 0, 0);
                acc[i][j] = __builtin_amdgcn_mfma_f32_16x16x32_bf16(ah[i], bl[j], acc[i][j], 0, 0, 0);
                acc[i][j] = __builtin_amdgcn_mfma_f32_16x16x32_bf16(al[i], bh[j], acc[i][j], 0, 0, 0);
            }
    }

    // C stores; C/D layout: col = lane&15, row = quad*4 + reg
#pragma unroll
    for (int i = 0; i < 4; ++i)
#pragma unroll
        for (int j = 0; j < 4; ++j) {
            int colC = colBase + wn * 64 + j * 16 + cl;
#pragma unroll
            for (int rr = 0; rr < 4; ++rr) {
                int rowC = rowBase + wm * 64 + i * 16 + quad * 4 + rr;
                if (rowC < M) C[(size_t)rowC * C_HID + colC] = acc[i][j][rr];
            }
        }

    // fused logits: partial row-dots with asrc/adst, cl-shuffle reduce, atomic accumulate
    float av[4], dv[4];
#pragma unroll
    for (int j = 0; j < 4; ++j) {
        int cn = colBase + wn * 64 + j * 16 + cl;
        av[j] = asrc[cn];
        dv[j] = adst[cn];
    }
#pragma unroll
    for (int i = 0; i < 4; ++i)
#pragma unroll
        for (int rr = 0; rr < 4; ++rr) {
            float s = 0.f, d = 0.f;
#pragma unroll
            for (int j = 0; j < 4; ++j) {
                float v = acc[i][j][rr];
                s = fmaf(v, av[j], s);
                d = fmaf(v, dv[j], d);
            }
#pragma unroll
            for (int o = 8; o >= 1; o >>= 1) {
                s += __shfl_xor(s, o);
                d += __shfl_xor(d, o);
            }
            int rowC = rowBase + wm * 64 + i * 16 + quad * 4 + rr;
            if (cl == 0 && rowC < M) {
                atomicAdd(&as_[rowC], s);
                atomicAdd(&ad_[rowC], d);
            }
        }
}

// ---------------- fused softmax + weighted gather: wave = (node, 128-col chunk) ----------------
// Edge list + softmax held in registers; inner loop = shuffle-broadcast + row load + FMA.
__global__ __launch_bounds__(256) void k_gather(const float* __restrict__ hW,
                                                const float* __restrict__ as_,
                                                const float* __restrict__ ad_,
                                                const int* __restrict__ rowptr,
                                                const int* __restrict__ col,
                                                const float* __restrict__ bias,
                                                unsigned short* __restrict__ outh,
                                                unsigned short* __restrict__ outl) {
    int wv = threadIdx.x >> 6, lane = threadIdx.x & 63;
    int node = blockIdx.x * 4 + wv;
    int c = blockIdx.y;
    if (node >= N_NODES) return;
    int start = rowptr[node], end = rowptr[node + 1];
    int deg = end - start;
    const float* base = hW + c * 128 + lane * 2;
    float ax = 0.f, ay = 0.f;
    float adi = ad_[node];

    if (deg <= 64) {
        // ---- register-resident path ----
        int col_v = col[start + min(lane, deg - 1)];          // coalesced
        float asv = as_[col_v];                                // 80 KB array -> L2 hit
        float logit = (lane < deg) ? leaky(asv + adi) : -1e30f;
        float m = logit;
#pragma unroll
        for (int o = 32; o; o >>= 1) m = fmaxf(m, __shfl_xor(m, o));
        float ex = __expf(logit - m);                          // inactive lanes -> 0
        float den = ex;
#pragma unroll
        for (int o = 32; o; o >>= 1) den += __shfl_xor(den, o);
        float alpha_v = ex / den;                              // per-lane edge weight

        for (int e0 = 0; e0 < deg; e0 += 8) {
            float2 r[8];
            float a[8];
#pragma unroll
            for (int q = 0; q < 8; ++q) {
                int e = e0 + q;
                int ec = min(e, deg - 1);                      // clamp: wasted loads hit L1
                int s = __shfl(col_v, ec);
                float ar = __shfl(alpha_v, ec);
                a[q] = (e < deg) ? ar : 0.f;
                r[q] = *(const float2*)(base + (size_t)s * C_HID);
            }
#pragma unroll
            for (int q = 0; q < 8; ++q) {
                ax = fmaf(a[q], r[q].x, ax);
                ay = fmaf(a[q], r[q].y, ay);
            }
        }
    } else {
        // ---- generic fallback (deg > 64; practically never taken) ----
        float m = -1e30f;
        for (int j = start + lane; j < end; j += 64)
            m = fmaxf(m, leaky(as_[col[j]] + adi));
        for (int o = 32; o; o >>= 1) m = fmaxf(m, __shfl_xor(m, o));
        float den = 0.f;
        for (int j = start + lane; j < end; j += 64)
            den += __expf(leaky(as_[col[j]] + adi) - m);
        for (int o = 32; o; o >>= 1) den += __shfl_xor(den, o);
        float inv = 1.f / den;
        for (int j = start; j < end; ++j) {
            int s = col[j];
            float a = __expf(leaky(as_[s] + adi) - m) * inv;
            float2 r = *(const float2*)(base + (size_t)s * C_HID);
            ax = fmaf(a, r.x, ax);
            ay = fmaf(a, r.y, ay);
        }
    }

    float2 b = *(const float2*)&bias[c * 128 + lane * 2];
    float v0 = fmaxf(ax + b.x, 0.f);   // layers 1-4 all have ReLU
    float v1 = fmaxf(ay + b.y, 0.f);
    unsigned short h0 = f2bf(v0), h1 = f2bf(v1);
    size_t o = (size_t)node * C_HID + c * 128 + lane * 2;
    *(ushort2*)&outh[o] = make_ushort2(h0, h1);
    *(ushort2*)&outl[o] = make_ushort2(f2bf(v0 - bf2f(h0)), f2bf(v1 - bf2f(h1)));
}

// ---------------- layer 5 (Co=2) ----------------
__global__ __launch_bounds__(256) void k_gemm2(const unsigned short* __restrict__ hh,
                                               const unsigned short* __restrict__ hl,
                                               const float* __restrict__ W,
                                               float* __restrict__ hW5) {
    int wave = (blockIdx.x * blockDim.x + threadIdx.x) >> 6;
    int lane = threadIdx.x & 63;
    if (wave >= N_NODES) return;
    const unsigned short* rh = hh + (size_t)wave * C_HID;
    const unsigned short* rl = hl + (size_t)wave * C_HID;
    float a0 = 0.f, a1 = 0.f;
#pragma unroll
    for (int k = lane; k < C_HID; k += 64) {
        float v = bf2f(rh[k]) + bf2f(rl[k]);
        a0 = fmaf(v, W[k * 2 + 0], a0);
        a1 = fmaf(v, W[k * 2 + 1], a1);
    }
    for (int o = 32; o; o >>= 1) { a0 += __shfl_xor(a0, o); a1 += __shfl_xor(a1, o); }
    if (lane == 0) { hW5[wave * 2 + 0] = a0; hW5[wave * 2 + 1] = a1; }
}

__global__ void k_logits2(const float* __restrict__ hW5, const float* __restrict__ asrc,
                          const float* __restrict__ adst,
                          float* __restrict__ as_, float* __restrict__ ad_) {
    int n = blockIdx.x * blockDim.x + threadIdx.x;
    if (n >= N_NODES) return;
    float h0 = hW5[n * 2], h1 = hW5[n * 2 + 1];
    as_[n] = h0 * asrc[0] + h1 * asrc[1];
    ad_[n] = h0 * adst[0] + h1 * adst[1];
}

__global__ void k_agg2(const float* __restrict__ hW5, const float* __restrict__ as_,
                       const float* __restrict__ ad_, const int* __restrict__ rowptr,
                       const int* __restrict__ col, const float* __restrict__ bias,
                       float* __restrict__ out) {
    int i = blockIdx.x * blockDim.x + threadIdx.x;
    if (i >= N_NODES) return;
    int start = rowptr[i], end = rowptr[i + 1];
    float adi = ad_[i];
    float m = -1e30f;
    for (int j = start; j < end; j++) m = fmaxf(m, leaky(as_[col[j]] + adi));
    float den = 0.f;
    for (int j = start; j < end; j++) den += __expf(leaky(as_[col[j]] + adi) - m);
    float inv = 1.f / den;
    float o0 = 0.f, o1 = 0.f;
    for (int j = start; j < end; j++) {
        int s = col[j];
        float al = __expf(leaky(as_[s] + adi) - m) * inv;
        o0 = fmaf(al, hW5[s * 2 + 0], o0);
        o1 = fmaf(al, hW5[s * 2 + 1], o1);
    }
    out[i * 2 + 0] = o0 + bias[0];
    out[i * 2 + 1] = o1 + bias[1];
}

extern "C" void kernel_launch(void* const* d_in, const int* in_sizes, int n_in,
                              void* d_out, int out_size, void* d_ws, size_t ws_size,
                              hipStream_t stream) {
    const float* x   = (const float*)d_in[0];
    const int*   ei  = (const int*)d_in[1];
    const float* W[5]  = {(const float*)d_in[2],  (const float*)d_in[6],
                          (const float*)d_in[10], (const float*)d_in[14],
                          (const float*)d_in[18]};
    const float* As[5] = {(const float*)d_in[3],  (const float*)d_in[7],
                          (const float*)d_in[11], (const float*)d_in[15],
                          (const float*)d_in[19]};
    const float* Ad[5] = {(const float*)d_in[4],  (const float*)d_in[8],
                          (const float*)d_in[12], (const float*)d_in[16],
                          (const float*)d_in[20]};
    const float* Bi[5] = {(const float*)d_in[5],  (const float*)d_in[9],
                          (const float*)d_in[13], (const float*)d_in[17],
                          (const float*)d_in[21]};
    float* out = (float*)d_out;

    // workspace layout (~107 MB)
    char* w = (char*)d_ws;
    float* bufX = (float*)w;                 w += (size_t)N_NODES * C_HID * 4;   // hW fp32
    unsigned short* pair_hi = (unsigned short*)w; w += (size_t)MPAD * C_HID * 2;
    unsigned short* pair_lo = (unsigned short*)w; w += (size_t)MPAD * C_HID * 2;
    unsigned short* Wth = (unsigned short*)w;     w += (size_t)C_HID * C_HID * 2;
    unsigned short* Wtl = (unsigned short*)w;     w += (size_t)C_HID * C_HID * 2;
    float* as_  = (float*)w;  w += N_NODES * 4;
    float* ad_  = (float*)w;  w += N_NODES * 4;   // contiguous after as_
    float* hW5  = (float*)w;  w += N_NODES * 2 * 4;
    int* rowptr = (int*)w;    w += (N_NODES + 1) * 4 + 12;
    int* counts = (int*)w;    w += N_NODES * 4;
    int* col    = (int*)w;    w += ET * 4;

    const int TB = 256;
    // ---- CSR build ----
    k_zero<<<(N_NODES + TB - 1) / TB, TB, 0, stream>>>(counts, N_NODES);
    k_count<<<(ET + TB - 1) / TB, TB, 0, stream>>>(ei, counts);
    k_scan<<<1, 1024, 0, stream>>>(counts, rowptr);
    k_copy<<<(N_NODES + TB - 1) / TB, TB, 0, stream>>>(rowptr, counts, N_NODES);
    k_fill<<<(ET + TB - 1) / TB, TB, 0, stream>>>(ei, counts, col);

    k_padzero<<<((MPAD - N_NODES) * C_HID + TB - 1) / TB, TB, 0, stream>>>(pair_hi, pair_lo);
    k_splitx<<<(MPAD * 128 / 4 + TB - 1) / TB, TB, 0, stream>>>(x, pair_hi, pair_lo);

    dim3 gemmGrid(MPAD / 128, C_HID / 128);   // 157 x 5
    dim3 gathGrid(N_NODES / 4, 5);            // 5000 x 5
    int nodeWaveBlocks = (N_NODES + 3) / 4;

    for (int l = 0; l <= 3; ++l) {
        int K = (l == 0) ? 128 : C_HID;
        k_zerof<<<(2 * N_NODES + TB - 1) / TB, TB, 0, stream>>>(as_, 2 * N_NODES);
        k_splitW<<<(K * C_HID + TB - 1) / TB, TB, 0, stream>>>(W[l], Wth, Wtl, K);
        k_mfma_gemm<<<gemmGrid, TB, 0, stream>>>(pair_hi, pair_lo, Wth, Wtl, bufX, K, N_NODES,
                                                 As[l], Ad[l], as_, ad_);
        k_gather<<<gathGrid, TB, 0, stream>>>(bufX, as_, ad_, rowptr, col, Bi[l], pair_hi, pair_lo);
    }

    // ---- layer 5: pair -> hW5 (N,2) -> out ----
    k_gemm2<<<nodeWaveBlocks, TB, 0, stream>>>(pair_hi, pair_lo, W[4], hW5);
    k_logits2<<<(N_NODES + TB - 1) / TB, TB, 0, stream>>>(hW5, As[4], Ad[4], as_, ad_);
    k_agg2<<<(N_NODES + TB - 1) / TB, TB, 0, stream>>>(hW5, as_, ad_, rowptr, col, Bi[4], out);
}